// Round 10
// baseline (1718.275 us; speedup 1.0000x reference)
//
#include <hip/hip_runtime.h>

#define B_ 16
#define N_ 4096
#define C_ 64
#define S_ 1024
#define K_ 32
#define CIN 67
#define O3 128
#define M_ (B_*S_*K_)   /* 524288 */
#define NBKT 64
#define EPS_ 1e-5f
#define FTH 256   /* fps threads */
#define FPT 16    /* fps points per thread */
#define XSTR 68   /* x_lds row stride (words): 68%32=4 bank rotation, 68*4%16==0 alignment */

__device__ __forceinline__ float sqd3(float dx, float dy, float dz){
  // match reference: ((dx*dx + dy*dy) + dz*dz), no fma contraction
  return __fadd_rn(__fadd_rn(__fmul_rn(dx,dx),__fmul_rn(dy,dy)),__fmul_rn(dz,dz));
}

__device__ __forceinline__ unsigned long long shfl_xor_u64(unsigned long long v, int off){
  unsigned lo = (unsigned)v, hi = (unsigned)(v>>32);
  lo = __shfl_xor(lo, off); hi = __shfl_xor(hi, off);
  return (((unsigned long long)hi)<<32)|lo;
}

// ---------------- FPS: one block per batch; 4 waves; dist-only inner loop ----------------
// argmax key u64 = (float_bits(dist)<<32) | ~n  -> max key == (max dist, min idx)
__global__ __launch_bounds__(FTH) void fps_kernel(const float* __restrict__ xyz,
    float* __restrict__ nxt /*B,S,3*/, float* __restrict__ out_xyz /*B,3,S*/){
  int b = blockIdx.x;
  const float* xb = xyz + (size_t)b*3*N_;
  __shared__ float xs[3*N_];
  __shared__ float selx[S_], sely[S_], selz[S_];
  __shared__ unsigned long long slot[2][4];
  int tid = threadIdx.x, lane = tid&63, w = tid>>6;
  for (int i=tid;i<3*N_;i+=FTH) xs[i]=xb[i];
  __syncthreads();
  float dist[FPT];
  #pragma unroll
  for (int j=0;j<FPT;j++) dist[j]=1e10f;
  int last = 0;
  for (int it=0; ; ++it){
    float lx=xs[last], ly=xs[N_+last], lz=xs[2*N_+last];
    if (tid==0){ selx[it]=lx; sely[it]=ly; selz[it]=lz; }
    if (it==S_-1) break;
    // dist update only (no per-point key work)
    #pragma unroll
    for (int j=0;j<FPT;j++){
      int n = tid + j*FTH;
      float dx=xs[n]-lx, dy=xs[N_+n]-ly, dz=xs[2*N_+n]-lz;
      float d = sqd3(dx,dy,dz);
      dist[j] = fminf(dist[j], d);
    }
    // per-thread argmax: ascending j + strict '>' keeps smallest n on ties
    float bd = dist[0]; int bn = tid;
    #pragma unroll
    for (int j=1;j<FPT;j++){
      if (dist[j] > bd){ bd = dist[j]; bn = tid + j*FTH; }
    }
    unsigned long long k = (((unsigned long long)__float_as_uint(bd))<<32) | (unsigned)(~bn);
    // 6-level xor butterfly (offsets 1..32); all lanes end with wave max
    #pragma unroll
    for (int off=1; off<64; off<<=1){
      unsigned long long k2 = shfl_xor_u64(k, off);
      if (k2 > k) k = k2;
    }
    if (lane==0) slot[it&1][w] = k;
    __syncthreads();
    unsigned long long kb = slot[it&1][0];
    #pragma unroll
    for (int ww=1; ww<4; ++ww){ unsigned long long k2 = slot[it&1][ww]; if (k2>kb) kb=k2; }
    last = (int)(~(unsigned)kb);
  }
  __syncthreads();
  for (int i=tid;i<S_;i+=FTH){
    out_xyz[(size_t)b*3*S_        + i] = selx[i];
    out_xyz[(size_t)b*3*S_ +   S_ + i] = sely[i];
    out_xyz[(size_t)b*3*S_ + 2*S_ + i] = selz[i];
  }
  for (int i=tid;i<3*S_;i+=FTH){
    int s = i/3, c = i - 3*s;
    float v = (c==0)?selx[s]:((c==1)?sely[s]:selz[s]);
    nxt[(size_t)b*3*S_ + i] = v;
  }
}

// ---------------- Ball query: one wave per query ----------------
__global__ __launch_bounds__(256) void ballq_kernel(const float* __restrict__ xyz,
    const float* __restrict__ nxt, int* __restrict__ idx){
  const float R2 = (float)(0.1*0.1);
  int lane = threadIdx.x & 63;
  int q = (blockIdx.x<<2) + (threadIdx.x>>6);
  int b = q >> 10;
  const float* xb = xyz + (size_t)b*3*N_;
  float qx = nxt[q*3+0], qy=nxt[q*3+1], qz=nxt[q*3+2];
  int* out = idx + (size_t)q*K_;
  int filled = 0; int first = N_;
  for (int n0=0; n0<N_ && filled<K_; n0+=64){
    int n = n0+lane;
    float dx = xb[n]-qx, dy=xb[N_+n]-qy, dz=xb[2*N_+n]-qz;
    float d = sqd3(dx,dy,dz);
    bool inb = (d <= R2);
    unsigned long long m = __ballot(inb);
    if (inb){
      int pos = filled + __popcll(m & ((1ull<<lane)-1ull));
      if (pos < K_) out[pos] = n;
    }
    if (first==N_ && m) first = n0 + (__ffsll((unsigned long long)m)-1);
    filled += __popcll(m);
  }
  if (filled < K_){
    if (first==N_) first = N_-1;
    for (int t = filled + lane; t < K_; t += 64) out[t] = first;
  }
}

// ---------------- transpose points (B,64,N) -> (B,N,64) ----------------
__global__ __launch_bounds__(256) void transpose_kernel(const float* __restrict__ pts,
    float* __restrict__ pts_t){
  __shared__ float t[64][65];
  int b = blockIdx.x >> 6;
  int n0 = (blockIdx.x & 63) << 6;
  const float* in = pts + (size_t)b*C_*N_;
  float* out = pts_t + (size_t)b*N_*C_;
  int tid=threadIdx.x;
  for (int i=tid;i<64*64;i+=256){ int c=i>>6, x=i&63; t[c][x]=in[(size_t)c*N_ + n0 + x]; }
  __syncthreads();
  for (int i=tid;i<64*64;i+=256){ int n=i>>6, c=i&63; out[(size_t)(n0+n)*C_ + c]=t[c][n]; }
}

// ------- weight transpose Wt[c][o] = W[o][c]; also zeroes stats (replaces memset) -------
__global__ __launch_bounds__(256) void wtrans_kernel(const float* __restrict__ W1,
    const float* __restrict__ W2, const float* __restrict__ W3,
    float* __restrict__ W1t, float* __restrict__ W2t, float* __restrict__ W3t,
    float* __restrict__ stats){
  int t0 = blockIdx.x*256 + threadIdx.x;
  int tot = gridDim.x*256;
  for (int i=t0;i<64*CIN;i+=tot){ int o=i/CIN, c=i-o*CIN; W1t[c*64+o]=W1[i]; }
  for (int i=t0;i<64*64;i+=tot){ int o=i>>6, c=i&63; W2t[c*64+o]=W2[i]; }
  for (int i=t0;i<128*64;i+=tot){ int o=i>>6, c=i&63; W3t[c*128+o]=W3[i]; }
  for (int i=t0;i<3*NBKT*2*128;i+=tot) stats[i]=0.f;
}

// ======== layer template: 256 thr, 64 rows (2 q) per block; x col-major in LDS,
// ======== W in LDS; thread (rg,cg) owns 4 rows x ncol cols of acc (registers only).

// ---------------- layer1: gather + relxyz + (67->64) + stats ----------------
__global__ __launch_bounds__(256) void layer1_kernel(const float* __restrict__ xyz,
    const float* __restrict__ pts_t, const float* __restrict__ nxt,
    const int* __restrict__ idx, const float* __restrict__ W1t,
    float* __restrict__ y1, float* __restrict__ stats){
  __shared__ __align__(16) float x_lds[CIN*XSTR];
  __shared__ __align__(16) float w_lds[CIN*64];
  __shared__ int sidx[64];
  __shared__ float sctr[2][3];
  int tid = threadIdx.x;
  int q0 = blockIdx.x*2; int b = q0>>10;
  if (tid<64) sidx[tid] = idx[(size_t)q0*K_ + tid];
  if (tid<6)  sctr[tid/3][tid%3] = nxt[(size_t)(q0 + tid/3)*3 + (tid%3)];
  for (int wI=tid; wI<CIN*64; wI+=256) w_lds[wI] = W1t[wI];
  __syncthreads();
  {
    int row = tid>>2, l4 = tid&3;
    int j = sidx[row];
    const float* prow = pts_t + ((size_t)b*N_ + j)*C_ + l4*16;
    #pragma unroll
    for (int h=0; h<4; ++h){
      float4 v = *(const float4*)(prow + h*4);
      int cb = 3 + l4*16 + h*4;
      x_lds[(cb+0)*XSTR + row] = v.x;
      x_lds[(cb+1)*XSTR + row] = v.y;
      x_lds[(cb+2)*XSTR + row] = v.z;
      x_lds[(cb+3)*XSTR + row] = v.w;
    }
    if (l4==0){
      const float* xb = xyz + (size_t)b*3*N_;
      int qh = row>>5;
      x_lds[0*XSTR+row] = xb[j]       - sctr[qh][0];
      x_lds[1*XSTR+row] = xb[N_ + j]  - sctr[qh][1];
      x_lds[2*XSTR+row] = xb[2*N_+j]  - sctr[qh][2];
    }
  }
  __syncthreads();
  int cg = tid & 15, rg = tid >> 4;
  float acc[4][4];
  #pragma unroll
  for (int i=0;i<4;i++)
    #pragma unroll
    for (int j=0;j<4;j++) acc[i][j]=0.f;
  for (int c=0;c<CIN;c++){
    float4 xv = *(const float4*)&x_lds[c*XSTR + rg*4];
    float4 wv = *(const float4*)&w_lds[c*64 + cg*4];
    float xr[4] = {xv.x,xv.y,xv.z,xv.w};
    float wr[4] = {wv.x,wv.y,wv.z,wv.w};
    #pragma unroll
    for (int i=0;i<4;i++)
      #pragma unroll
      for (int j=0;j<4;j++) acc[i][j] = fmaf(xr[i], wr[j], acc[i][j]);
  }
  // write y1 col-major: y[(q*64+col)*32 + r32]
  int q = q0 + (rg>>3), r32 = (rg&7)*4;
  #pragma unroll
  for (int j=0;j<4;j++){
    float4 o = {acc[0][j], acc[1][j], acc[2][j], acc[3][j]};
    *(float4*)&y1[((size_t)q*64 + cg*4 + j)*32 + r32] = o;
  }
  // stats
  float cs[4], cq[4];
  #pragma unroll
  for (int j=0;j<4;j++){
    cs[j] = ((acc[0][j]+acc[1][j])+(acc[2][j]+acc[3][j]));
    cq[j] = fmaf(acc[0][j],acc[0][j], fmaf(acc[1][j],acc[1][j],
            fmaf(acc[2][j],acc[2][j], acc[3][j]*acc[3][j])));
  }
  #pragma unroll
  for (int off=16; off<64; off<<=1)
    #pragma unroll
    for (int j=0;j<4;j++){ cs[j]+=__shfl_xor(cs[j],off); cq[j]+=__shfl_xor(cq[j],off); }
  if ((tid&63)<16){
    int bkt = blockIdx.x & (NBKT-1);
    #pragma unroll
    for (int j=0;j<4;j++){
      atomicAdd(&stats[(size_t)(bkt*2+0)*128 + cg*4+j], cs[j]);
      atomicAdd(&stats[(size_t)(bkt*2+1)*128 + cg*4+j], cq[j]);
    }
  }
}

// ---------------- layer2: bn1+relu + (64->64) IN-PLACE + stats ----------------
__global__ __launch_bounds__(256) void layer2_kernel(float* __restrict__ ybuf,
    const float* __restrict__ W2t, const float* __restrict__ st1,
    float* __restrict__ stats){
  __shared__ __align__(16) float x_lds[64*XSTR];
  __shared__ __align__(16) float w_lds[64*64];
  int tid = threadIdx.x;
  int q0 = blockIdx.x*2;
  for (int wI=tid; wI<64*64; wI+=256) w_lds[wI] = W2t[wI];
  const float* ybase = ybuf + (size_t)q0*2048;
  #pragma unroll
  for (int k=0;k<4;k++){
    int u = tid + k*256;                 // chunk 0..1023
    int qh = u>>9, c = (u>>3)&63, r4 = (u&7)<<2;
    float4 v = *(const float4*)(ybase + (size_t)u*4);
    float sc = st1[c], sh = st1[128+c];
    float4 o;
    o.x = fmaf(v.x, sc, sh); o.x = o.x>0.f?o.x:0.f;
    o.y = fmaf(v.y, sc, sh); o.y = o.y>0.f?o.y:0.f;
    o.z = fmaf(v.z, sc, sh); o.z = o.z>0.f?o.z:0.f;
    o.w = fmaf(v.w, sc, sh); o.w = o.w>0.f?o.w:0.f;
    *(float4*)&x_lds[c*XSTR + qh*32 + r4] = o;
  }
  __syncthreads();   // all in-place-source reads complete before any store below
  int cg = tid & 15, rg = tid >> 4;
  float acc[4][4];
  #pragma unroll
  for (int i=0;i<4;i++)
    #pragma unroll
    for (int j=0;j<4;j++) acc[i][j]=0.f;
  for (int c=0;c<64;c++){
    float4 xv = *(const float4*)&x_lds[c*XSTR + rg*4];
    float4 wv = *(const float4*)&w_lds[c*64 + cg*4];
    float xr[4] = {xv.x,xv.y,xv.z,xv.w};
    float wr[4] = {wv.x,wv.y,wv.z,wv.w};
    #pragma unroll
    for (int i=0;i<4;i++)
      #pragma unroll
      for (int j=0;j<4;j++) acc[i][j] = fmaf(xr[i], wr[j], acc[i][j]);
  }
  int q = q0 + (rg>>3), r32 = (rg&7)*4;
  #pragma unroll
  for (int j=0;j<4;j++){
    float4 o = {acc[0][j], acc[1][j], acc[2][j], acc[3][j]};
    *(float4*)&ybuf[((size_t)q*64 + cg*4 + j)*32 + r32] = o;
  }
  float cs[4], cq[4];
  #pragma unroll
  for (int j=0;j<4;j++){
    cs[j] = ((acc[0][j]+acc[1][j])+(acc[2][j]+acc[3][j]));
    cq[j] = fmaf(acc[0][j],acc[0][j], fmaf(acc[1][j],acc[1][j],
            fmaf(acc[2][j],acc[2][j], acc[3][j]*acc[3][j])));
  }
  #pragma unroll
  for (int off=16; off<64; off<<=1)
    #pragma unroll
    for (int j=0;j<4;j++){ cs[j]+=__shfl_xor(cs[j],off); cq[j]+=__shfl_xor(cq[j],off); }
  if ((tid&63)<16){
    int bkt = blockIdx.x & (NBKT-1);
    #pragma unroll
    for (int j=0;j<4;j++){
      atomicAdd(&stats[(size_t)(bkt*2+0)*128 + cg*4+j], cs[j]);
      atomicAdd(&stats[(size_t)(bkt*2+1)*128 + cg*4+j], cq[j]);
    }
  }
}

// ---------------- layer3: bn2+relu + (64->128) + per-q max + stats ----------------
__global__ __launch_bounds__(256) void layer3_kernel(const float* __restrict__ ybuf,
    const float* __restrict__ W3t, const float* __restrict__ st2,
    float* __restrict__ m3, float* __restrict__ stats){
  __shared__ __align__(16) float x_lds[64*XSTR];
  __shared__ __align__(16) float w_lds[64*O3];
  __shared__ float mred[4][O3];
  int tid = threadIdx.x;
  int q0 = blockIdx.x*2;
  for (int wI=tid; wI<64*O3; wI+=256) w_lds[wI] = W3t[wI];
  const float* ybase = ybuf + (size_t)q0*2048;
  #pragma unroll
  for (int k=0;k<4;k++){
    int u = tid + k*256;
    int qh = u>>9, c = (u>>3)&63, r4 = (u&7)<<2;
    float4 v = *(const float4*)(ybase + (size_t)u*4);
    float sc = st2[c], sh = st2[128+c];
    float4 o;
    o.x = fmaf(v.x, sc, sh); o.x = o.x>0.f?o.x:0.f;
    o.y = fmaf(v.y, sc, sh); o.y = o.y>0.f?o.y:0.f;
    o.z = fmaf(v.z, sc, sh); o.z = o.z>0.f?o.z:0.f;
    o.w = fmaf(v.w, sc, sh); o.w = o.w>0.f?o.w:0.f;
    *(float4*)&x_lds[c*XSTR + qh*32 + r4] = o;
  }
  __syncthreads();
  int cg = tid & 15, rg = tid >> 4;
  float acc[4][8];
  #pragma unroll
  for (int i=0;i<4;i++)
    #pragma unroll
    for (int j=0;j<8;j++) acc[i][j]=0.f;
  for (int c=0;c<64;c++){
    float4 xv = *(const float4*)&x_lds[c*XSTR + rg*4];
    float4 wv0 = *(const float4*)&w_lds[c*O3 + cg*8];
    float4 wv1 = *(const float4*)&w_lds[c*O3 + cg*8 + 4];
    float xr[4] = {xv.x,xv.y,xv.z,xv.w};
    float wr[8] = {wv0.x,wv0.y,wv0.z,wv0.w, wv1.x,wv1.y,wv1.z,wv1.w};
    #pragma unroll
    for (int i=0;i<4;i++)
      #pragma unroll
      for (int j=0;j<8;j++) acc[i][j] = fmaf(xr[i], wr[j], acc[i][j]);
  }
  // per-col: partial sum, sumsq, max over this thread's 4 rows
  float cs[8], cq[8], cm[8];
  #pragma unroll
  for (int j=0;j<8;j++){
    cs[j] = ((acc[0][j]+acc[1][j])+(acc[2][j]+acc[3][j]));
    cq[j] = fmaf(acc[0][j],acc[0][j], fmaf(acc[1][j],acc[1][j],
            fmaf(acc[2][j],acc[2][j], acc[3][j]*acc[3][j])));
    cm[j] = fmaxf(fmaxf(acc[0][j],acc[1][j]), fmaxf(acc[2][j],acc[3][j]));
  }
  #pragma unroll
  for (int off=16; off<64; off<<=1)
    #pragma unroll
    for (int j=0;j<8;j++){
      cs[j]+=__shfl_xor(cs[j],off); cq[j]+=__shfl_xor(cq[j],off);
      cm[j] = fmaxf(cm[j], __shfl_xor(cm[j],off));
    }
  int wid = tid>>6;
  if ((tid&63)<16){
    int bkt = blockIdx.x & (NBKT-1);
    #pragma unroll
    for (int j=0;j<8;j++){
      atomicAdd(&stats[(size_t)(bkt*2+0)*128 + cg*8+j], cs[j]);
      atomicAdd(&stats[(size_t)(bkt*2+1)*128 + cg*8+j], cq[j]);
      mred[wid][cg*8+j] = cm[j];
    }
  }
  __syncthreads();
  // waves {0,1} hold q0 partial maxima, {2,3} hold q1
  {
    int ch = tid & 127, qh = tid >> 7;
    float v = fmaxf(mred[qh*2][ch], mred[qh*2+1][ch]);
    m3[(size_t)(q0+qh)*O3 + ch] = v;
  }
}

// ---------------- BN finalize ----------------
__global__ void finalize_kernel(const float* __restrict__ stats, const float* __restrict__ g,
    const float* __restrict__ bias, float* __restrict__ st, int Cc){
  int o=threadIdx.x; if (o>=Cc) return;
  float sum=0.f, ss=0.f;
  for (int k=0;k<NBKT;k++){ sum+=stats[((size_t)k*2+0)*128+o]; ss+=stats[((size_t)k*2+1)*128+o]; }
  const float invM = 1.0f/(float)M_;
  float mu = sum*invM;
  float var = ss*invM - mu*mu;
  if (var<0.f) var=0.f;
  float s = g[o] / sqrtf(var+EPS_);
  st[o]=s; st[128+o]=bias[o]-mu*s;
}

// ---------------- epilogue: bn3+relu on max, tiled transpose to (B,128,S) ----------------
__global__ __launch_bounds__(256) void out_kernel(const float* __restrict__ m3,
    const float* __restrict__ st3, float* __restrict__ out){
  __shared__ float tile[32][33];
  int b = blockIdx.x, s0 = blockIdx.y*32, o0 = blockIdx.z*32;
  int tid = threadIdx.x;
  {
    int i = tid>>3, jj = (tid&7)*4;
    const float* src = m3 + ((size_t)b*S_ + s0 + i)*O3 + o0 + jj;
    float4 v = *(const float4*)src;
    float4 sc = *(const float4*)&st3[o0+jj];
    float4 sh = *(const float4*)&st3[128+o0+jj];
    float r0 = fmaf(v.x, sc.x, sh.x); tile[i][jj+0] = r0>0.f?r0:0.f;
    float r1 = fmaf(v.y, sc.y, sh.y); tile[i][jj+1] = r1>0.f?r1:0.f;
    float r2 = fmaf(v.z, sc.z, sh.z); tile[i][jj+2] = r2>0.f?r2:0.f;
    float r3 = fmaf(v.w, sc.w, sh.w); tile[i][jj+3] = r3>0.f?r3:0.f;
  }
  __syncthreads();
  {
    int o = tid>>3, ss = (tid&7)*4;
    float4 v = {tile[ss+0][o], tile[ss+1][o], tile[ss+2][o], tile[ss+3][o]};
    *(float4*)&out[((size_t)b*O3 + o0 + o)*S_ + s0 + ss] = v;
  }
}

extern "C" void kernel_launch(void* const* d_in, const int* in_sizes, int n_in,
                              void* d_out, int out_size, void* d_ws, size_t ws_size,
                              hipStream_t stream){
  const float* xyz = (const float*)d_in[0];
  const float* pts = (const float*)d_in[1];
  const float* W1  = (const float*)d_in[2];
  const float* g1  = (const float*)d_in[3];
  const float* b1  = (const float*)d_in[4];
  const float* W2  = (const float*)d_in[5];
  const float* g2  = (const float*)d_in[6];
  const float* b2  = (const float*)d_in[7];
  const float* W3  = (const float*)d_in[8];
  const float* g3  = (const float*)d_in[9];
  const float* b3  = (const float*)d_in[10];
  float* out = (float*)d_out;

  char* ws = (char*)d_ws;
  size_t off=0;
  auto alloc=[&](size_t bytes)->char*{ char* p=ws+off; off += (bytes+255)&~255ull; return p; };
  float* nxt     = (float*)alloc((size_t)B_*S_*3*4);
  int*   idx     = (int*)  alloc((size_t)B_*S_*K_*4);
  float* pts_t   = (float*)alloc((size_t)B_*N_*C_*4);
  float* stats   = (float*)alloc((size_t)3*NBKT*2*128*4);
  float* st1     = (float*)alloc(256*4);
  float* st2     = (float*)alloc(256*4);
  float* st3     = (float*)alloc(256*4);
  float* W1t     = (float*)alloc((size_t)CIN*64*4);
  float* W2t     = (float*)alloc((size_t)64*64*4);
  float* W3t     = (float*)alloc((size_t)64*128*4);
  float* m3      = (float*)alloc((size_t)B_*S_*O3*4);
  float* ybuf    = (float*)alloc((size_t)M_*64*4);   // y1 col-major, then y2 in-place

  float* stats1 = stats;
  float* stats2 = stats + (size_t)NBKT*2*128;
  float* stats3 = stats + (size_t)2*NBKT*2*128;

  hipLaunchKernelGGL(wtrans_kernel, dim3(32), dim3(256), 0, stream, W1, W2, W3, W1t, W2t, W3t, stats);
  hipLaunchKernelGGL(transpose_kernel, dim3(B_*64), dim3(256), 0, stream, pts, pts_t);
  hipLaunchKernelGGL(fps_kernel,   dim3(B_),      dim3(FTH), 0, stream, xyz, nxt, out);
  hipLaunchKernelGGL(ballq_kernel, dim3(B_*S_/4), dim3(256), 0, stream, xyz, nxt, idx);
  hipLaunchKernelGGL(layer1_kernel,dim3(B_*S_/2), dim3(256), 0, stream, xyz, pts_t, nxt, idx, W1t, ybuf, stats1);
  hipLaunchKernelGGL(finalize_kernel, dim3(1), dim3(128), 0, stream, stats1, g1, b1, st1, 64);
  hipLaunchKernelGGL(layer2_kernel,dim3(B_*S_/2), dim3(256), 0, stream, ybuf, W2t, st1, stats2);
  hipLaunchKernelGGL(finalize_kernel, dim3(1), dim3(128), 0, stream, stats2, g2, b2, st2, 64);
  hipLaunchKernelGGL(layer3_kernel,dim3(B_*S_/2), dim3(256), 0, stream, ybuf, W3t, st2, m3, stats3);
  hipLaunchKernelGGL(finalize_kernel, dim3(1), dim3(128), 0, stream, stats3, g3, b3, st3, 128);
  hipLaunchKernelGGL(out_kernel, dim3(B_, S_/32, O3/32), dim3(256), 0, stream, m3, st3, out + (size_t)B_*3*S_);
}

// Round 12
// 1611.864 us; speedup vs baseline: 1.0660x; 1.0660x over previous
//
#include <hip/hip_runtime.h>

#define B_ 16
#define N_ 4096
#define C_ 64
#define S_ 1024
#define K_ 32
#define CIN 67
#define O3 128
#define M_ (B_*S_*K_)   /* 524288 */
#define NBKT 64
#define EPS_ 1e-5f
#define FTH 256   /* fps threads */
#define FPT 16    /* fps points per thread */
#define XSTR 68   /* x_lds row stride (words): 68%32=4 bank rotation, 68*4%16==0 alignment */

__device__ __forceinline__ float sqd3(float dx, float dy, float dz){
  // match reference: ((dx*dx + dy*dy) + dz*dz), no fma contraction
  return __fadd_rn(__fadd_rn(__fmul_rn(dx,dx),__fmul_rn(dy,dy)),__fmul_rn(dz,dz));
}

// ---- wave64 reduce via DPP (VALU-speed; avoids ds_swizzle ~120cyc/level latency) ----
// row_shr:1/2/4/8 then row_bcast:15/31 -> lane 63 holds full-wave result.
// old=v + bound_ctrl=false => invalid-source lanes keep v (identity for max/min).
__device__ __forceinline__ float wave_max_f32(float v){
  #define DPPSTEP(ctrl) { int t_ = __builtin_amdgcn_update_dpp(__float_as_int(v), __float_as_int(v), (ctrl), 0xF, 0xF, false); \
                          float tf_ = __int_as_float(t_); v = fmaxf(v, tf_); }
  DPPSTEP(0x111) DPPSTEP(0x112) DPPSTEP(0x114) DPPSTEP(0x118) DPPSTEP(0x142) DPPSTEP(0x143)
  #undef DPPSTEP
  return __int_as_float(__builtin_amdgcn_readlane(__float_as_int(v), 63));
}
__device__ __forceinline__ unsigned wave_min_u32(unsigned v){
  #define DPPSTEP(ctrl) { unsigned t_ = (unsigned)__builtin_amdgcn_update_dpp((int)v, (int)v, (ctrl), 0xF, 0xF, false); \
                          v = (v < t_) ? v : t_; }
  DPPSTEP(0x111) DPPSTEP(0x112) DPPSTEP(0x114) DPPSTEP(0x118) DPPSTEP(0x142) DPPSTEP(0x143)
  #undef DPPSTEP
  return (unsigned)__builtin_amdgcn_readlane((int)v, 63);
}

// ---------------- FPS: one block per batch; 4 waves; DPP wave reduce ----------------
__global__ __launch_bounds__(FTH) void fps_kernel(const float* __restrict__ xyz,
    float* __restrict__ nxt /*B,S,3*/, float* __restrict__ out_xyz /*B,3,S*/){
  int b = blockIdx.x;
  const float* xb = xyz + (size_t)b*3*N_;
  __shared__ float xs[3*N_];
  __shared__ float selx[S_], sely[S_], selz[S_];
  __shared__ unsigned long long slot[2][4];
  int tid = threadIdx.x, lane = tid&63, w = tid>>6;
  for (int i=tid;i<3*N_;i+=FTH) xs[i]=xb[i];
  __syncthreads();
  float dist[FPT];
  #pragma unroll
  for (int j=0;j<FPT;j++) dist[j]=1e10f;
  int last = 0;
  for (int it=0; ; ++it){
    float lx=xs[last], ly=xs[N_+last], lz=xs[2*N_+last];
    if (tid==0){ selx[it]=lx; sely[it]=ly; selz[it]=lz; }
    if (it==S_-1) break;
    #pragma unroll
    for (int j=0;j<FPT;j++){
      int n = tid + j*FTH;
      float dx=xs[n]-lx, dy=xs[N_+n]-ly, dz=xs[2*N_+n]-lz;
      float d = sqd3(dx,dy,dz);
      dist[j] = fminf(dist[j], d);
    }
    // per-thread argmax: ascending j + strict '>' keeps smallest n on ties
    float bd = dist[0]; int bn = tid;
    #pragma unroll
    for (int j=1;j<FPT;j++){
      if (dist[j] > bd){ bd = dist[j]; bn = tid + j*FTH; }
    }
    // phase 1: wave max of dist (exact); phase 2: min index among max-achieving lanes
    float wm = wave_max_f32(bd);
    unsigned cand = (bd == wm) ? (unsigned)bn : 0xFFFFFFFFu;
    unsigned wi = wave_min_u32(cand);
    if (lane==0)
      slot[it&1][w] = (((unsigned long long)__float_as_uint(wm))<<32) | (unsigned)(~wi);
    __syncthreads();
    unsigned long long kb = slot[it&1][0];
    #pragma unroll
    for (int ww=1; ww<4; ++ww){ unsigned long long k2 = slot[it&1][ww]; if (k2>kb) kb=k2; }
    last = (int)(~(unsigned)kb);
  }
  __syncthreads();
  for (int i=tid;i<S_;i+=FTH){
    out_xyz[(size_t)b*3*S_        + i] = selx[i];
    out_xyz[(size_t)b*3*S_ +   S_ + i] = sely[i];
    out_xyz[(size_t)b*3*S_ + 2*S_ + i] = selz[i];
  }
  for (int i=tid;i<3*S_;i+=FTH){
    int s = i/3, c = i - 3*s;
    float v = (c==0)?selx[s]:((c==1)?sely[s]:selz[s]);
    nxt[(size_t)b*3*S_ + i] = v;
  }
}

// ---------------- Ball query: one wave per query ----------------
__global__ __launch_bounds__(256) void ballq_kernel(const float* __restrict__ xyz,
    const float* __restrict__ nxt, int* __restrict__ idx){
  const float R2 = (float)(0.1*0.1);
  int lane = threadIdx.x & 63;
  int q = (blockIdx.x<<2) + (threadIdx.x>>6);
  int b = q >> 10;
  const float* xb = xyz + (size_t)b*3*N_;
  float qx = nxt[q*3+0], qy=nxt[q*3+1], qz=nxt[q*3+2];
  int* out = idx + (size_t)q*K_;
  int filled = 0; int first = N_;
  for (int n0=0; n0<N_ && filled<K_; n0+=64){
    int n = n0+lane;
    float dx = xb[n]-qx, dy=xb[N_+n]-qy, dz=xb[2*N_+n]-qz;
    float d = sqd3(dx,dy,dz);
    bool inb = (d <= R2);
    unsigned long long m = __ballot(inb);
    if (inb){
      int pos = filled + __popcll(m & ((1ull<<lane)-1ull));
      if (pos < K_) out[pos] = n;
    }
    if (first==N_ && m) first = n0 + (__ffsll((unsigned long long)m)-1);
    filled += __popcll(m);
  }
  if (filled < K_){
    if (first==N_) first = N_-1;
    for (int t = filled + lane; t < K_; t += 64) out[t] = first;
  }
}

// ---------------- transpose points (B,64,N) -> (B,N,64) ----------------
__global__ __launch_bounds__(256) void transpose_kernel(const float* __restrict__ pts,
    float* __restrict__ pts_t){
  __shared__ float t[64][65];
  int b = blockIdx.x >> 6;
  int n0 = (blockIdx.x & 63) << 6;
  const float* in = pts + (size_t)b*C_*N_;
  float* out = pts_t + (size_t)b*N_*C_;
  int tid=threadIdx.x;
  for (int i=tid;i<64*64;i+=256){ int c=i>>6, x=i&63; t[c][x]=in[(size_t)c*N_ + n0 + x]; }
  __syncthreads();
  for (int i=tid;i<64*64;i+=256){ int n=i>>6, c=i&63; out[(size_t)(n0+n)*C_ + c]=t[c][n]; }
}

// ------- weight transpose Wt[c][o] = W[o][c]; also zeroes stats (replaces memset) -------
__global__ __launch_bounds__(256) void wtrans_kernel(const float* __restrict__ W1,
    const float* __restrict__ W2, const float* __restrict__ W3,
    float* __restrict__ W1t, float* __restrict__ W2t, float* __restrict__ W3t,
    float* __restrict__ stats){
  int t0 = blockIdx.x*256 + threadIdx.x;
  int tot = gridDim.x*256;
  for (int i=t0;i<64*CIN;i+=tot){ int o=i/CIN, c=i-o*CIN; W1t[c*64+o]=W1[i]; }
  for (int i=t0;i<64*64;i+=tot){ int o=i>>6, c=i&63; W2t[c*64+o]=W2[i]; }
  for (int i=t0;i<128*64;i+=tot){ int o=i>>6, c=i&63; W3t[c*128+o]=W3[i]; }
  for (int i=t0;i<3*NBKT*2*128;i+=tot) stats[i]=0.f;
}

// ======== layer template: 256 thr, 64 rows (2 q) per block; x col-major in LDS,
// ======== W in LDS; thread (rg,cg) owns 4 rows x ncol cols of acc (registers only).

// ---------------- layer1: gather + relxyz + (67->64) + stats ----------------
__global__ __launch_bounds__(256) void layer1_kernel(const float* __restrict__ xyz,
    const float* __restrict__ pts_t, const float* __restrict__ nxt,
    const int* __restrict__ idx, const float* __restrict__ W1t,
    float* __restrict__ y1, float* __restrict__ stats){
  __shared__ __align__(16) float x_lds[CIN*XSTR];
  __shared__ __align__(16) float w_lds[CIN*64];
  __shared__ int sidx[64];
  __shared__ float sctr[2][3];
  int tid = threadIdx.x;
  int q0 = blockIdx.x*2; int b = q0>>10;
  if (tid<64) sidx[tid] = idx[(size_t)q0*K_ + tid];
  if (tid<6)  sctr[tid/3][tid%3] = nxt[(size_t)(q0 + tid/3)*3 + (tid%3)];
  for (int wI=tid; wI<CIN*64; wI+=256) w_lds[wI] = W1t[wI];
  __syncthreads();
  {
    int row = tid>>2, l4 = tid&3;
    int j = sidx[row];
    const float* prow = pts_t + ((size_t)b*N_ + j)*C_ + l4*16;
    #pragma unroll
    for (int h=0; h<4; ++h){
      float4 v = *(const float4*)(prow + h*4);
      int cb = 3 + l4*16 + h*4;
      x_lds[(cb+0)*XSTR + row] = v.x;
      x_lds[(cb+1)*XSTR + row] = v.y;
      x_lds[(cb+2)*XSTR + row] = v.z;
      x_lds[(cb+3)*XSTR + row] = v.w;
    }
    if (l4==0){
      const float* xb = xyz + (size_t)b*3*N_;
      int qh = row>>5;
      x_lds[0*XSTR+row] = xb[j]       - sctr[qh][0];
      x_lds[1*XSTR+row] = xb[N_ + j]  - sctr[qh][1];
      x_lds[2*XSTR+row] = xb[2*N_+j]  - sctr[qh][2];
    }
  }
  __syncthreads();
  int cg = tid & 15, rg = tid >> 4;
  float acc[4][4];
  #pragma unroll
  for (int i=0;i<4;i++)
    #pragma unroll
    for (int j=0;j<4;j++) acc[i][j]=0.f;
  for (int c=0;c<CIN;c++){
    float4 xv = *(const float4*)&x_lds[c*XSTR + rg*4];
    float4 wv = *(const float4*)&w_lds[c*64 + cg*4];
    float xr[4] = {xv.x,xv.y,xv.z,xv.w};
    float wr[4] = {wv.x,wv.y,wv.z,wv.w};
    #pragma unroll
    for (int i=0;i<4;i++)
      #pragma unroll
      for (int j=0;j<4;j++) acc[i][j] = fmaf(xr[i], wr[j], acc[i][j]);
  }
  // write y1 col-major: y[(q*64+col)*32 + r32]
  int q = q0 + (rg>>3), r32 = (rg&7)*4;
  #pragma unroll
  for (int j=0;j<4;j++){
    float4 o = {acc[0][j], acc[1][j], acc[2][j], acc[3][j]};
    *(float4*)&y1[((size_t)q*64 + cg*4 + j)*32 + r32] = o;
  }
  // stats
  float cs[4], cq[4];
  #pragma unroll
  for (int j=0;j<4;j++){
    cs[j] = ((acc[0][j]+acc[1][j])+(acc[2][j]+acc[3][j]));
    cq[j] = fmaf(acc[0][j],acc[0][j], fmaf(acc[1][j],acc[1][j],
            fmaf(acc[2][j],acc[2][j], acc[3][j]*acc[3][j])));
  }
  #pragma unroll
  for (int off=16; off<64; off<<=1)
    #pragma unroll
    for (int j=0;j<4;j++){ cs[j]+=__shfl_xor(cs[j],off); cq[j]+=__shfl_xor(cq[j],off); }
  if ((tid&63)<16){
    int bkt = blockIdx.x & (NBKT-1);
    #pragma unroll
    for (int j=0;j<4;j++){
      atomicAdd(&stats[(size_t)(bkt*2+0)*128 + cg*4+j], cs[j]);
      atomicAdd(&stats[(size_t)(bkt*2+1)*128 + cg*4+j], cq[j]);
    }
  }
}

// ---------------- layer2: bn1+relu + (64->64) IN-PLACE + stats ----------------
__global__ __launch_bounds__(256) void layer2_kernel(float* __restrict__ ybuf,
    const float* __restrict__ W2t, const float* __restrict__ st1,
    float* __restrict__ stats){
  __shared__ __align__(16) float x_lds[64*XSTR];
  __shared__ __align__(16) float w_lds[64*64];
  int tid = threadIdx.x;
  int q0 = blockIdx.x*2;
  for (int wI=tid; wI<64*64; wI+=256) w_lds[wI] = W2t[wI];
  const float* ybase = ybuf + (size_t)q0*2048;
  #pragma unroll
  for (int k=0;k<4;k++){
    int u = tid + k*256;                 // chunk 0..1023
    int qh = u>>9, c = (u>>3)&63, r4 = (u&7)<<2;
    float4 v = *(const float4*)(ybase + (size_t)u*4);
    float sc = st1[c], sh = st1[128+c];
    float4 o;
    o.x = fmaf(v.x, sc, sh); o.x = o.x>0.f?o.x:0.f;
    o.y = fmaf(v.y, sc, sh); o.y = o.y>0.f?o.y:0.f;
    o.z = fmaf(v.z, sc, sh); o.z = o.z>0.f?o.z:0.f;
    o.w = fmaf(v.w, sc, sh); o.w = o.w>0.f?o.w:0.f;
    *(float4*)&x_lds[c*XSTR + qh*32 + r4] = o;
  }
  __syncthreads();   // all in-place-source reads complete before any store below
  int cg = tid & 15, rg = tid >> 4;
  float acc[4][4];
  #pragma unroll
  for (int i=0;i<4;i++)
    #pragma unroll
    for (int j=0;j<4;j++) acc[i][j]=0.f;
  for (int c=0;c<64;c++){
    float4 xv = *(const float4*)&x_lds[c*XSTR + rg*4];
    float4 wv = *(const float4*)&w_lds[c*64 + cg*4];
    float xr[4] = {xv.x,xv.y,xv.z,xv.w};
    float wr[4] = {wv.x,wv.y,wv.z,wv.w};
    #pragma unroll
    for (int i=0;i<4;i++)
      #pragma unroll
      for (int j=0;j<4;j++) acc[i][j] = fmaf(xr[i], wr[j], acc[i][j]);
  }
  int q = q0 + (rg>>3), r32 = (rg&7)*4;
  #pragma unroll
  for (int j=0;j<4;j++){
    float4 o = {acc[0][j], acc[1][j], acc[2][j], acc[3][j]};
    *(float4*)&ybuf[((size_t)q*64 + cg*4 + j)*32 + r32] = o;
  }
  float cs[4], cq[4];
  #pragma unroll
  for (int j=0;j<4;j++){
    cs[j] = ((acc[0][j]+acc[1][j])+(acc[2][j]+acc[3][j]));
    cq[j] = fmaf(acc[0][j],acc[0][j], fmaf(acc[1][j],acc[1][j],
            fmaf(acc[2][j],acc[2][j], acc[3][j]*acc[3][j])));
  }
  #pragma unroll
  for (int off=16; off<64; off<<=1)
    #pragma unroll
    for (int j=0;j<4;j++){ cs[j]+=__shfl_xor(cs[j],off); cq[j]+=__shfl_xor(cq[j],off); }
  if ((tid&63)<16){
    int bkt = blockIdx.x & (NBKT-1);
    #pragma unroll
    for (int j=0;j<4;j++){
      atomicAdd(&stats[(size_t)(bkt*2+0)*128 + cg*4+j], cs[j]);
      atomicAdd(&stats[(size_t)(bkt*2+1)*128 + cg*4+j], cq[j]);
    }
  }
}

// ---------------- layer3: bn2+relu + (64->128) + per-q max + stats ----------------
__global__ __launch_bounds__(256) void layer3_kernel(const float* __restrict__ ybuf,
    const float* __restrict__ W3t, const float* __restrict__ st2,
    float* __restrict__ m3, float* __restrict__ stats){
  __shared__ __align__(16) float x_lds[64*XSTR];
  __shared__ __align__(16) float w_lds[64*O3];
  __shared__ float mred[4][O3];
  int tid = threadIdx.x;
  int q0 = blockIdx.x*2;
  for (int wI=tid; wI<64*O3; wI+=256) w_lds[wI] = W3t[wI];
  const float* ybase = ybuf + (size_t)q0*2048;
  #pragma unroll
  for (int k=0;k<4;k++){
    int u = tid + k*256;
    int qh = u>>9, c = (u>>3)&63, r4 = (u&7)<<2;
    float4 v = *(const float4*)(ybase + (size_t)u*4);
    float sc = st2[c], sh = st2[128+c];
    float4 o;
    o.x = fmaf(v.x, sc, sh); o.x = o.x>0.f?o.x:0.f;
    o.y = fmaf(v.y, sc, sh); o.y = o.y>0.f?o.y:0.f;
    o.z = fmaf(v.z, sc, sh); o.z = o.z>0.f?o.z:0.f;
    o.w = fmaf(v.w, sc, sh); o.w = o.w>0.f?o.w:0.f;
    *(float4*)&x_lds[c*XSTR + qh*32 + r4] = o;
  }
  __syncthreads();
  int cg = tid & 15, rg = tid >> 4;
  float acc[4][8];
  #pragma unroll
  for (int i=0;i<4;i++)
    #pragma unroll
    for (int j=0;j<8;j++) acc[i][j]=0.f;
  for (int c=0;c<64;c++){
    float4 xv = *(const float4*)&x_lds[c*XSTR + rg*4];
    float4 wv0 = *(const float4*)&w_lds[c*O3 + cg*8];
    float4 wv1 = *(const float4*)&w_lds[c*O3 + cg*8 + 4];
    float xr[4] = {xv.x,xv.y,xv.z,xv.w};
    float wr[8] = {wv0.x,wv0.y,wv0.z,wv0.w, wv1.x,wv1.y,wv1.z,wv1.w};
    #pragma unroll
    for (int i=0;i<4;i++)
      #pragma unroll
      for (int j=0;j<8;j++) acc[i][j] = fmaf(xr[i], wr[j], acc[i][j]);
  }
  // per-col: partial sum, sumsq, max over this thread's 4 rows
  float cs[8], cq[8], cm[8];
  #pragma unroll
  for (int j=0;j<8;j++){
    cs[j] = ((acc[0][j]+acc[1][j])+(acc[2][j]+acc[3][j]));
    cq[j] = fmaf(acc[0][j],acc[0][j], fmaf(acc[1][j],acc[1][j],
            fmaf(acc[2][j],acc[2][j], acc[3][j]*acc[3][j])));
    cm[j] = fmaxf(fmaxf(acc[0][j],acc[1][j]), fmaxf(acc[2][j],acc[3][j]));
  }
  #pragma unroll
  for (int off=16; off<64; off<<=1)
    #pragma unroll
    for (int j=0;j<8;j++){
      cs[j]+=__shfl_xor(cs[j],off); cq[j]+=__shfl_xor(cq[j],off);
      cm[j] = fmaxf(cm[j], __shfl_xor(cm[j],off));
    }
  int wid = tid>>6;
  if ((tid&63)<16){
    int bkt = blockIdx.x & (NBKT-1);
    #pragma unroll
    for (int j=0;j<8;j++){
      atomicAdd(&stats[(size_t)(bkt*2+0)*128 + cg*8+j], cs[j]);
      atomicAdd(&stats[(size_t)(bkt*2+1)*128 + cg*8+j], cq[j]);
      mred[wid][cg*8+j] = cm[j];
    }
  }
  __syncthreads();
  // waves {0,1} hold q0 partial maxima, {2,3} hold q1
  {
    int ch = tid & 127, qh = tid >> 7;
    float v = fmaxf(mred[qh*2][ch], mred[qh*2+1][ch]);
    m3[(size_t)(q0+qh)*O3 + ch] = v;
  }
}

// ---------------- BN finalize ----------------
__global__ void finalize_kernel(const float* __restrict__ stats, const float* __restrict__ g,
    const float* __restrict__ bias, float* __restrict__ st, int Cc){
  int o=threadIdx.x; if (o>=Cc) return;
  float sum=0.f, ss=0.f;
  for (int k=0;k<NBKT;k++){ sum+=stats[((size_t)k*2+0)*128+o]; ss+=stats[((size_t)k*2+1)*128+o]; }
  const float invM = 1.0f/(float)M_;
  float mu = sum*invM;
  float var = ss*invM - mu*mu;
  if (var<0.f) var=0.f;
  float s = g[o] / sqrtf(var+EPS_);
  st[o]=s; st[128+o]=bias[o]-mu*s;
}

// ---------------- epilogue: bn3+relu on max, tiled transpose to (B,128,S) ----------------
__global__ __launch_bounds__(256) void out_kernel(const float* __restrict__ m3,
    const float* __restrict__ st3, float* __restrict__ out){
  __shared__ float tile[32][33];
  int b = blockIdx.x, s0 = blockIdx.y*32, o0 = blockIdx.z*32;
  int tid = threadIdx.x;
  {
    int i = tid>>3, jj = (tid&7)*4;
    const float* src = m3 + ((size_t)b*S_ + s0 + i)*O3 + o0 + jj;
    float4 v = *(const float4*)src;
    float4 sc = *(const float4*)&st3[o0+jj];
    float4 sh = *(const float4*)&st3[128+o0+jj];
    float r0 = fmaf(v.x, sc.x, sh.x); tile[i][jj+0] = r0>0.f?r0:0.f;
    float r1 = fmaf(v.y, sc.y, sh.y); tile[i][jj+1] = r1>0.f?r1:0.f;
    float r2 = fmaf(v.z, sc.z, sh.z); tile[i][jj+2] = r2>0.f?r2:0.f;
    float r3 = fmaf(v.w, sc.w, sh.w); tile[i][jj+3] = r3>0.f?r3:0.f;
  }
  __syncthreads();
  {
    int o = tid>>3, ss = (tid&7)*4;
    float4 v = {tile[ss+0][o], tile[ss+1][o], tile[ss+2][o], tile[ss+3][o]};
    *(float4*)&out[((size_t)b*O3 + o0 + o)*S_ + s0 + ss] = v;
  }
}

extern "C" void kernel_launch(void* const* d_in, const int* in_sizes, int n_in,
                              void* d_out, int out_size, void* d_ws, size_t ws_size,
                              hipStream_t stream){
  const float* xyz = (const float*)d_in[0];
  const float* pts = (const float*)d_in[1];
  const float* W1  = (const float*)d_in[2];
  const float* g1  = (const float*)d_in[3];
  const float* b1  = (const float*)d_in[4];
  const float* W2  = (const float*)d_in[5];
  const float* g2  = (const float*)d_in[6];
  const float* b2  = (const float*)d_in[7];
  const float* W3  = (const float*)d_in[8];
  const float* g3  = (const float*)d_in[9];
  const float* b3  = (const float*)d_in[10];
  float* out = (float*)d_out;

  char* ws = (char*)d_ws;
  size_t off=0;
  auto alloc=[&](size_t bytes)->char*{ char* p=ws+off; off += (bytes+255)&~255ull; return p; };
  float* nxt     = (float*)alloc((size_t)B_*S_*3*4);
  int*   idx     = (int*)  alloc((size_t)B_*S_*K_*4);
  float* pts_t   = (float*)alloc((size_t)B_*N_*C_*4);
  float* stats   = (float*)alloc((size_t)3*NBKT*2*128*4);
  float* st1     = (float*)alloc(256*4);
  float* st2     = (float*)alloc(256*4);
  float* st3     = (float*)alloc(256*4);
  float* W1t     = (float*)alloc((size_t)CIN*64*4);
  float* W2t     = (float*)alloc((size_t)64*64*4);
  float* W3t     = (float*)alloc((size_t)64*128*4);
  float* m3      = (float*)alloc((size_t)B_*S_*O3*4);
  float* ybuf    = (float*)alloc((size_t)M_*64*4);   // y1 col-major, then y2 in-place

  float* stats1 = stats;
  float* stats2 = stats + (size_t)NBKT*2*128;
  float* stats3 = stats + (size_t)2*NBKT*2*128;

  hipLaunchKernelGGL(wtrans_kernel, dim3(32), dim3(256), 0, stream, W1, W2, W3, W1t, W2t, W3t, stats);
  hipLaunchKernelGGL(transpose_kernel, dim3(B_*64), dim3(256), 0, stream, pts, pts_t);
  hipLaunchKernelGGL(fps_kernel,   dim3(B_),      dim3(FTH), 0, stream, xyz, nxt, out);
  hipLaunchKernelGGL(ballq_kernel, dim3(B_*S_/4), dim3(256), 0, stream, xyz, nxt, idx);
  hipLaunchKernelGGL(layer1_kernel,dim3(B_*S_/2), dim3(256), 0, stream, xyz, pts_t, nxt, idx, W1t, ybuf, stats1);
  hipLaunchKernelGGL(finalize_kernel, dim3(1), dim3(128), 0, stream, stats1, g1, b1, st1, 64);
  hipLaunchKernelGGL(layer2_kernel,dim3(B_*S_/2), dim3(256), 0, stream, ybuf, W2t, st1, stats2);
  hipLaunchKernelGGL(finalize_kernel, dim3(1), dim3(128), 0, stream, stats2, g2, b2, st2, 64);
  hipLaunchKernelGGL(layer3_kernel,dim3(B_*S_/2), dim3(256), 0, stream, ybuf, W3t, st2, m3, stats3);
  hipLaunchKernelGGL(finalize_kernel, dim3(1), dim3(128), 0, stream, stats3, g3, b3, st3, 128);
  hipLaunchKernelGGL(out_kernel, dim3(B_, S_/32, O3/32), dim3(256), 0, stream, m3, st3, out + (size_t)B_*3*S_);
}